// Round 8
// baseline (111.588 us; speedup 1.0000x reference)
//
#include <hip/hip_runtime.h>
#include <math.h>

// Problem constants (fixed by the reference): Q=4096 queries, N=65536 train, D=32.
#define QN 4096
#define NN 65536
#define DD 32

typedef __attribute__((ext_vector_type(8))) _Float16 half8;
typedef __attribute__((ext_vector_type(4))) _Float16 half4v;
typedef __attribute__((ext_vector_type(4))) float floatx4;

#define LOG2E 1.4426950408889634f
#define HALF_D_LOG_2PI 29.40603306254953f   // 16 * ln(2*pi)

// exp2-in-MFMA scaling: A = x*log2(e)*2^11, B = y*2^12, C = 127*2^23.
// MFMA emits v = (127 + x.y*log2e)*2^23 == the float bit pattern of
// 2^(x.y*log2e) under the linear-mantissa approximation. Per element:
// med3 clamp -> cvt_i32 -> fmac = 3 full-rate VALU ops. Validated R5-R7
// (absmax 0.25, identical to real exp2 -> error dominated by f16 rounding).
#define ASCALE 2954.6394357789634f   // log2(e) * 2048
#define BSCALE 4096.0f               // 2^12
#define BIAS_F 1065353216.0f         // 127 * 2^23
#define CAPF   1585446912.0f         // (127+62) * 2^23  (keeps cvt < INT_MAX)
#define CENTER 0.970656f             // centers the one-sided approx error

__device__ __forceinline__ float fexp_term(float v) {
    v = __builtin_amdgcn_fmed3f(v, 0.0f, CAPF);   // single v_med3_f32
    return __int_as_float((int)v);
}

// LDS B-tile row stride in halves: 32 data + 8 pad = 40 (80 B = 20 dwords).
// Bank for lane(q,l): (20*l + 4*q + w) mod 32 has period 8 in l -> only
// 2-way aliasing, which is free (m136). 16B alignment preserved (80 % 16 == 0).
#define PS 40

// ---------------------------------------------------------------------------
// Workspace layout (bytes):
//   Xh    @ 0        : QN*DD*2 = 262144   (_Float16, X * ASCALE)
//   Xth   @ 262144   : NN*DD*2 = 4194304  (_Float16, X_train * BSCALE)
//   c     @ 4456448  : NN*4    = 262144   (CENTER * w_j * exp(-||y_j||^2/2))
//   qn    @ 4718592  : QN*4    = 16384    (||x_i||^2 / 2, nat units)
//   S     @ 4734976  : QN*4    = 16384    (zeroed by prep_all)
//   swp   @ 4751360  : 64*4    = 256      (per-block partial sums of w)
// ---------------------------------------------------------------------------

// Fused prep: blocks [0,128) convert X (+ zero S), [128,2176) convert
// X_train + c, [2176,2240) reduce sum(w) into per-block partials.
// No fences, no cross-block protocol (R5 lesson: agent fences cost ~140us).
__global__ __launch_bounds__(256) void prep_all(
    const float* __restrict__ X, const float* __restrict__ Xt,
    const float* __restrict__ w, _Float16* __restrict__ Xh,
    float* __restrict__ qn, _Float16* __restrict__ Xth,
    float* __restrict__ c, float* __restrict__ S,
    float* __restrict__ swp) {
    const int b = blockIdx.x;
    if (b < 128) {                       // ---- prep X: QN rows, 8 lanes/row
        int tid  = b * 256 + threadIdx.x;
        int row  = tid >> 3;
        int part = tid & 7;
        const float4 v = ((const float4*)X)[row * 8 + part];
        float nrm = v.x * v.x + v.y * v.y + v.z * v.z + v.w * v.w;
        nrm += __shfl_xor(nrm, 1);
        nrm += __shfl_xor(nrm, 2);
        nrm += __shfl_xor(nrm, 4);
        half4v h = { (_Float16)(v.x * ASCALE), (_Float16)(v.y * ASCALE),
                     (_Float16)(v.z * ASCALE), (_Float16)(v.w * ASCALE) };
        *(half4v*)(Xh + row * DD + part * 4) = h;
        if (part == 0) qn[row] = 0.5f * nrm;
        if (tid < QN) S[tid] = 0.f;      // fused zeroing of S
    } else if (b < 2176) {               // ---- prep X_train: NN rows
        int tid  = (b - 128) * 256 + threadIdx.x;
        int row  = tid >> 3;
        int part = tid & 7;
        const float4 v = ((const float4*)Xt)[row * 8 + part];
        float nrm = v.x * v.x + v.y * v.y + v.z * v.z + v.w * v.w;
        nrm += __shfl_xor(nrm, 1);
        nrm += __shfl_xor(nrm, 2);
        nrm += __shfl_xor(nrm, 4);
        half4v h = { (_Float16)(v.x * BSCALE), (_Float16)(v.y * BSCALE),
                     (_Float16)(v.z * BSCALE), (_Float16)(v.w * BSCALE) };
        *(half4v*)(Xth + row * DD + part * 4) = h;
        if (part == 0)
            c[row] = w[row] * __builtin_amdgcn_exp2f(-0.5f * LOG2E * nrm) * CENTER;
    } else {                             // ---- sum(w) partials: 64 blocks
        int bid = b - 2176;
        float v = 0.f;
        for (int i = bid * 256 + threadIdx.x; i < NN; i += 64 * 256)
            v += w[i];
        #pragma unroll
        for (int o = 1; o < 64; o <<= 1) v += __shfl_xor(v, o);
        __shared__ float red[4];
        if ((threadIdx.x & 63) == 0) red[threadIdx.x >> 6] = v;
        __syncthreads();
        if (threadIdx.x == 0) swp[bid] = red[0] + red[1] + red[2] + red[3];
    }
}

// Main kernel: per block, 256 queries x strip of 512 train points.
// B/c staged through double-buffered LDS shared by the 4 waves: 8 chunks
// of 64 train points; each thread stages 16 B/chunk issued one full
// compute-chunk before its ds_write (structural latency hiding). Inner
// consumption is ds_read_b128 from padded rows. XCD-swizzled 1-D grid.
__global__ __launch_bounds__(256) void kde_main(
    const _Float16* __restrict__ Xh, const _Float16* __restrict__ Xth,
    const float* __restrict__ c, float* __restrict__ S) {
    const int t      = threadIdx.x;
    const int lane   = t & 63;
    const int wave   = t >> 6;
    const int quad   = lane >> 4;
    const int l16    = lane & 15;

    // XCD swizzle (R7-proven: FETCH 17.5 -> 3.2 MB): blocks with equal
    // (b & 7) share an XCD and a strip set (512 KB of Xth -> L2-resident).
    const int b      = blockIdx.x;            // 0..2047
    const int xcd    = b & 7;
    const int slot   = b >> 3;                // 0..255
    const int qx     = slot & 15;             // query tile 0..15
    const int strip  = xcd + 8 * (slot >> 4); // 0..127
    const int m_base = qx * 256 + wave * 64;
    const int n_beg  = strip * 512;

    // Double-buffered LDS: 64 train rows x 40 halves (+pad), plus c.
    __shared__ __align__(16) _Float16 bbuf[2][64 * PS];   // 2 x 5120 B
    __shared__ float cbuf[2][64];                         // 2 x 256 B

    // A fragments: 4 tiles of 16 queries, resident for the whole strip.
    half8 a0 = *(const half8*)(Xh + (m_base +  0 + l16) * DD + quad * 8);
    half8 a1 = *(const half8*)(Xh + (m_base + 16 + l16) * DD + quad * 8);
    half8 a2 = *(const half8*)(Xh + (m_base + 32 + l16) * DD + quad * 8);
    half8 a3 = *(const half8*)(Xh + (m_base + 48 + l16) * DD + quad * 8);

    // Staging addresses: thread t covers row r = t/4, halves [(t%4)*8, +8).
    const int r   = t >> 2;
    const int col = (t & 3) * 8;
    const _Float16* gb = Xth + (size_t)n_beg * DD + t * 8;

    // Stage chunk 0.
    half8 st = *(const half8*)gb;
    float sc = (t < 64) ? c[n_beg + t] : 0.f;
    *(half8*)&bbuf[0][r * PS + col] = st;
    if (t < 64) cbuf[0][t] = sc;
    __syncthreads();

    float s0[4][4] = {};
    float s1[4][4] = {};
    const floatx4 cbias = {BIAS_F, BIAS_F, BIAS_F, BIAS_F};

    for (int ch = 0; ch < 8; ++ch) {
        const int p = ch & 1;

        // Prefetch next chunk into registers (consumed by ds_write AFTER
        // this chunk's compute -- the compute hides the global latency).
        half8 nst;
        float nsc = 0.f;
        if (ch < 7) {
            gb += 64 * DD;
            nst = *(const half8*)gb;
            if (t < 64) nsc = c[n_beg + (ch + 1) * 64 + t];
        }

        // Compute on chunk ch: 4 B-tiles of 16 train points.
        #pragma unroll
        for (int j = 0; j < 4; ++j) {
            half8 bj = *(const half8*)&bbuf[p][(j * 16 + l16) * PS + quad * 8];
            float cj = cbuf[p][j * 16 + l16];

            floatx4 g0 = __builtin_amdgcn_mfma_f32_16x16x32_f16(a0, bj, cbias, 0, 0, 0);
            floatx4 g1 = __builtin_amdgcn_mfma_f32_16x16x32_f16(a1, bj, cbias, 0, 0, 0);
            floatx4 g2 = __builtin_amdgcn_mfma_f32_16x16x32_f16(a2, bj, cbias, 0, 0, 0);
            floatx4 g3 = __builtin_amdgcn_mfma_f32_16x16x32_f16(a3, bj, cbias, 0, 0, 0);

            float (*s)[4] = (j & 1) ? s1 : s0;   // two accumulation chains
            #pragma unroll
            for (int rr = 0; rr < 4; ++rr) {
                s[0][rr] += cj * fexp_term(g0[rr]);
                s[1][rr] += cj * fexp_term(g1[rr]);
                s[2][rr] += cj * fexp_term(g2[rr]);
                s[3][rr] += cj * fexp_term(g3[rr]);
            }
        }

        // Write next chunk into the other buffer, then barrier.
        if (ch < 7) {
            *(half8*)&bbuf[p ^ 1][r * PS + col] = nst;
            if (t < 64) cbuf[p ^ 1][t] = nsc;
        }
        __syncthreads();
    }

    // Reduce over the 16 columns (lanes sharing the same quad), then atomic.
    #pragma unroll
    for (int tt = 0; tt < 4; ++tt) {
        #pragma unroll
        for (int rr = 0; rr < 4; ++rr) {
            float v = s0[tt][rr] + s1[tt][rr];
            v += __shfl_xor(v, 1);
            v += __shfl_xor(v, 2);
            v += __shfl_xor(v, 4);
            v += __shfl_xor(v, 8);
            if (l16 == 0)
                atomicAdd(&S[m_base + tt * 16 + quad * 4 + rr], v);
        }
    }
}

// Finalize: 16 blocks x 256 threads; sums the 64 w-partials via shuffle.
__global__ void finalize(const float* __restrict__ S, const float* __restrict__ qn,
                         const float* __restrict__ swp, float* __restrict__ out) {
    float pv = swp[threadIdx.x & 63];
    pv += __shfl_xor(pv, 1);
    pv += __shfl_xor(pv, 2);
    pv += __shfl_xor(pv, 4);
    pv += __shfl_xor(pv, 8);
    pv += __shfl_xor(pv, 16);
    pv += __shfl_xor(pv, 32);
    float lsw = logf(pv);
    int i = blockIdx.x * blockDim.x + threadIdx.x;
    out[i] = logf(S[i]) - qn[i] - HALF_D_LOG_2PI - lsw;
}

extern "C" void kernel_launch(void* const* d_in, const int* in_sizes, int n_in,
                              void* d_out, int out_size, void* d_ws, size_t ws_size,
                              hipStream_t stream) {
    const float* X  = (const float*)d_in[0];
    const float* Xt = (const float*)d_in[1];
    const float* w  = (const float*)d_in[2];
    float* out = (float*)d_out;

    char* ws = (char*)d_ws;
    _Float16* Xh   = (_Float16*)(ws);
    _Float16* Xth  = (_Float16*)(ws + 262144);
    float*    c    = (float*)(ws + 4456448);
    float*    qn   = (float*)(ws + 4718592);
    float*    S    = (float*)(ws + 4734976);
    float*    swp  = (float*)(ws + 4751360);

    prep_all<<<2240, 256, 0, stream>>>(X, Xt, w, Xh, qn, Xth, c, S, swp);
    kde_main<<<2048, 256, 0, stream>>>(Xh, Xth, c, S);
    finalize<<<QN / 256, 256, 0, stream>>>(S, qn, swp, out);
}

// Round 10
// 105.961 us; speedup vs baseline: 1.0531x; 1.0531x over previous
//
#include <hip/hip_runtime.h>
#include <math.h>

// Problem constants (fixed by the reference): Q=4096 queries, N=65536 train, D=32.
#define QN 4096
#define NN 65536
#define DD 32

typedef __attribute__((ext_vector_type(8))) _Float16 half8;
typedef __attribute__((ext_vector_type(4))) _Float16 half4v;
typedef __attribute__((ext_vector_type(4))) float floatx4;

#define LOG2E 1.4426950408889634f
#define HALF_D_LOG_2PI 29.40603306254953f   // 16 * ln(2*pi)

// exp2-in-MFMA scaling: A = x*log2(e)*2^11, B = y*2^12, C = 127*2^23.
// MFMA emits v = (127 + x.y*log2e)*2^23 == the float bit pattern of
// 2^(x.y*log2e) under the linear-mantissa approximation. Per element:
// med3 clamp -> cvt_i32 -> fmac. R9 removed the clamp and FAILED (absmax
// 11.75 vs 0.25) -- the clamp is load-bearing on real data; KEEP IT.
#define ASCALE 2954.6394357789634f   // log2(e) * 2048
#define BSCALE 4096.0f               // 2^12
#define BIAS_F 1065353216.0f         // 127 * 2^23
#define CAPF   1585446912.0f         // (127+62) * 2^23  (keeps cvt < INT_MAX)
#define CENTER 0.970656f             // centers the one-sided approx error

__device__ __forceinline__ float fexp_term(float v) {
    v = __builtin_amdgcn_fmed3f(v, 0.0f, CAPF);   // single v_med3_f32
    return __int_as_float((int)v);
}

// ---------------------------------------------------------------------------
// Workspace layout (bytes):
//   Xh    @ 0        : QN*DD*2 = 262144   (_Float16, X * ASCALE)
//   Xth   @ 262144   : NN*DD*2 = 4194304  (_Float16, X_train * BSCALE)
//   c     @ 4456448  : NN*4    = 262144   (CENTER * w_j * exp(-||y_j||^2/2))
//   qn    @ 4718592  : QN*4    = 16384    (||x_i||^2 / 2, nat units)
//   S     @ 4734976  : QN*4    = 16384    (zeroed by prep_all)
//   swp   @ 4751360  : 64*4    = 256      (per-block partial sums of w)
// Prefetch over-read: kde_main reads <= 1 tile past Xth/c strip ends; lands
// in the adjacent ws regions (c/qn) -- in-bounds, values discarded.
// ---------------------------------------------------------------------------

__global__ __launch_bounds__(256) void prep_all(
    const float* __restrict__ X, const float* __restrict__ Xt,
    const float* __restrict__ w, _Float16* __restrict__ Xh,
    float* __restrict__ qn, _Float16* __restrict__ Xth,
    float* __restrict__ c, float* __restrict__ S,
    float* __restrict__ swp) {
    const int b = blockIdx.x;
    if (b < 128) {                       // ---- prep X: QN rows, 8 lanes/row
        int tid  = b * 256 + threadIdx.x;
        int row  = tid >> 3;
        int part = tid & 7;
        const float4 v = ((const float4*)X)[row * 8 + part];
        float nrm = v.x * v.x + v.y * v.y + v.z * v.z + v.w * v.w;
        nrm += __shfl_xor(nrm, 1);
        nrm += __shfl_xor(nrm, 2);
        nrm += __shfl_xor(nrm, 4);
        half4v h = { (_Float16)(v.x * ASCALE), (_Float16)(v.y * ASCALE),
                     (_Float16)(v.z * ASCALE), (_Float16)(v.w * ASCALE) };
        *(half4v*)(Xh + row * DD + part * 4) = h;
        if (part == 0) qn[row] = 0.5f * nrm;
        if (tid < QN) S[tid] = 0.f;      // fused zeroing of S
    } else if (b < 2176) {               // ---- prep X_train: NN rows
        int tid  = (b - 128) * 256 + threadIdx.x;
        int row  = tid >> 3;
        int part = tid & 7;
        const float4 v = ((const float4*)Xt)[row * 8 + part];
        float nrm = v.x * v.x + v.y * v.y + v.z * v.z + v.w * v.w;
        nrm += __shfl_xor(nrm, 1);
        nrm += __shfl_xor(nrm, 2);
        nrm += __shfl_xor(nrm, 4);
        half4v h = { (_Float16)(v.x * BSCALE), (_Float16)(v.y * BSCALE),
                     (_Float16)(v.z * BSCALE), (_Float16)(v.w * BSCALE) };
        *(half4v*)(Xth + row * DD + part * 4) = h;
        if (part == 0)
            c[row] = w[row] * __builtin_amdgcn_exp2f(-0.5f * LOG2E * nrm) * CENTER;
    } else {                             // ---- sum(w) partials: 64 blocks
        int bid = b - 2176;
        float v = 0.f;
        for (int i = bid * 256 + threadIdx.x; i < NN; i += 64 * 256)
            v += w[i];
        #pragma unroll
        for (int o = 1; o < 64; o <<= 1) v += __shfl_xor(v, o);
        __shared__ float red[4];
        if ((threadIdx.x & 63) == 0) red[threadIdx.x >> 6] = v;
        __syncthreads();
        if (threadIdx.x == 0) swp[bid] = red[0] + red[1] + red[2] + red[3];
    }
}

// Main kernel: per wave, 64 queries x strip of 512 train points.
// MFMA results software-pipelined one iteration deep: iteration it issues
// 8 MFMAs on tile-pair it, then runs the clamped epilogue on pair it-1's
// results (MFMA->VALU hazard distance = a full iteration). B/c loads keep
// distance-1 prefetch. XCD-swizzled 1-D grid (R7: FETCH 17.5 -> 3.2 MB).
__global__ __launch_bounds__(256) void kde_main(
    const _Float16* __restrict__ Xh, const _Float16* __restrict__ Xth,
    const float* __restrict__ c, float* __restrict__ S) {
    const int lane   = threadIdx.x & 63;
    const int wave   = threadIdx.x >> 6;
    const int quad   = lane >> 4;
    const int l16    = lane & 15;

    const int b      = blockIdx.x;            // 0..2047
    const int xcd    = b & 7;
    const int slot   = b >> 3;                // 0..255
    const int qx     = slot & 15;             // query tile 0..15
    const int strip  = xcd + 8 * (slot >> 4); // 0..127
    const int m_base = qx * 256 + wave * 64;
    const int n_beg  = strip * 512;

    // A fragments: 4 tiles of 16 queries, resident for the whole strip.
    half8 a[4];
    #pragma unroll
    for (int t = 0; t < 4; ++t)
        a[t] = *(const half8*)(Xh + (m_base + t * 16 + l16) * DD + quad * 8);

    float s[4][4] = {};                       // merged accumulators
    const floatx4 cbias = {BIAS_F, BIAS_F, BIAS_F, BIAS_F};

    const _Float16* bp = Xth + (size_t)(n_beg + l16) * DD + quad * 8;
    const float*    cp = c + n_beg + l16;

    // --- software-pipeline prologue -------------------------------------
    half8 b0 = *(const half8*)bp;
    half8 b1 = *(const half8*)(bp + 16 * DD);
    float cA0 = cp[0], cA1 = cp[16];          // c for gp (epilogue)

    floatx4 gp[4][2];
    #pragma unroll
    for (int t = 0; t < 4; ++t) {
        gp[t][0] = __builtin_amdgcn_mfma_f32_16x16x32_f16(a[t], b0, cbias, 0, 0, 0);
        gp[t][1] = __builtin_amdgcn_mfma_f32_16x16x32_f16(a[t], b1, cbias, 0, 0, 0);
    }
    bp += 32 * DD;
    cp += 32;
    half8 nb0 = *(const half8*)bp;
    half8 nb1 = *(const half8*)(bp + 16 * DD);
    float cB0 = cp[0], cB1 = cp[16];          // c for the b feeding next MFMAs

    for (int it = 1; it < 16; ++it) {
        // MFMAs for pair `it` (operands loaded last iteration).
        floatx4 gn[4][2];
        #pragma unroll
        for (int t = 0; t < 4; ++t) {
            gn[t][0] = __builtin_amdgcn_mfma_f32_16x16x32_f16(a[t], nb0, cbias, 0, 0, 0);
            gn[t][1] = __builtin_amdgcn_mfma_f32_16x16x32_f16(a[t], nb1, cbias, 0, 0, 0);
        }

        // Prefetch pair it+1 (last iteration over-reads one pair -- dead).
        bp += 32 * DD;
        cp += 32;
        nb0 = *(const half8*)bp;
        nb1 = *(const half8*)(bp + 16 * DD);
        float ncB0 = cp[0], ncB1 = cp[16];

        // Epilogue on pair it-1 (gp): med3 clamp + cvt + fmac per element.
        #pragma unroll
        for (int t = 0; t < 4; ++t) {
            #pragma unroll
            for (int r = 0; r < 4; ++r) {
                s[t][r] += cA0 * fexp_term(gp[t][0][r]);
                s[t][r] += cA1 * fexp_term(gp[t][1][r]);
            }
        }

        // Rotate pipeline state.
        #pragma unroll
        for (int t = 0; t < 4; ++t) {
            gp[t][0] = gn[t][0];
            gp[t][1] = gn[t][1];
        }
        cA0 = cB0; cA1 = cB1;
        cB0 = ncB0; cB1 = ncB1;
    }

    // Drain: epilogue on the last pair.
    #pragma unroll
    for (int t = 0; t < 4; ++t) {
        #pragma unroll
        for (int r = 0; r < 4; ++r) {
            s[t][r] += cA0 * fexp_term(gp[t][0][r]);
            s[t][r] += cA1 * fexp_term(gp[t][1][r]);
        }
    }

    // Reduce over the 16 columns (lanes sharing the same quad), then atomic.
    #pragma unroll
    for (int t = 0; t < 4; ++t) {
        #pragma unroll
        for (int r = 0; r < 4; ++r) {
            float v = s[t][r];
            v += __shfl_xor(v, 1);
            v += __shfl_xor(v, 2);
            v += __shfl_xor(v, 4);
            v += __shfl_xor(v, 8);
            if (l16 == 0)
                atomicAdd(&S[m_base + t * 16 + quad * 4 + r], v);
        }
    }
}

// Finalize: 16 blocks x 256 threads; sums the 64 w-partials via shuffle.
__global__ void finalize(const float* __restrict__ S, const float* __restrict__ qn,
                         const float* __restrict__ swp, float* __restrict__ out) {
    float pv = swp[threadIdx.x & 63];
    pv += __shfl_xor(pv, 1);
    pv += __shfl_xor(pv, 2);
    pv += __shfl_xor(pv, 4);
    pv += __shfl_xor(pv, 8);
    pv += __shfl_xor(pv, 16);
    pv += __shfl_xor(pv, 32);
    float lsw = logf(pv);
    int i = blockIdx.x * blockDim.x + threadIdx.x;
    out[i] = logf(S[i]) - qn[i] - HALF_D_LOG_2PI - lsw;
}

extern "C" void kernel_launch(void* const* d_in, const int* in_sizes, int n_in,
                              void* d_out, int out_size, void* d_ws, size_t ws_size,
                              hipStream_t stream) {
    const float* X  = (const float*)d_in[0];
    const float* Xt = (const float*)d_in[1];
    const float* w  = (const float*)d_in[2];
    float* out = (float*)d_out;

    char* ws = (char*)d_ws;
    _Float16* Xh   = (_Float16*)(ws);
    _Float16* Xth  = (_Float16*)(ws + 262144);
    float*    c    = (float*)(ws + 4456448);
    float*    qn   = (float*)(ws + 4718592);
    float*    S    = (float*)(ws + 4734976);
    float*    swp  = (float*)(ws + 4751360);

    prep_all<<<2240, 256, 0, stream>>>(X, Xt, w, Xh, qn, Xth, c, S, swp);
    kde_main<<<2048, 256, 0, stream>>>(Xh, Xth, c, S);
    finalize<<<QN / 256, 256, 0, stream>>>(S, qn, swp, out);
}